// Round 6
// baseline (887.011 us; speedup 1.0000x reference)
//
#include <hip/hip_runtime.h>

#define T_LEN 1024
#define IN_DIM 128
#define HID 64
#define CH 8              // steps per x-stage / out-flush chunk
#define NCH (T_LEN / CH)  // 128 chunks
#define ROWS 2            // batch chains per block (M=2 in the MFMA tile)
// LDS row strides. XSTR/HSTR (shorts): 320B/192B == 16 dwords (mod 32) ->
// 2-way bank aliasing on b128 A-frag reads = free (validated R4/R5).
// OSTR (floats): 288B.
#define XSTR 160
#define HSTR 96
#define OSTR 72

typedef __attribute__((ext_vector_type(8))) short short8;
typedef __attribute__((ext_vector_type(4))) float floatx4;

__device__ __forceinline__ unsigned short f2bf(float v) {
    union { float f; unsigned u; } a; a.f = v;
    unsigned r = a.u + 0x7FFFu + ((a.u >> 16) & 1u);  // RNE, no NaN inputs here
    return (unsigned short)(r >> 16);
}

__device__ __forceinline__ short8 cvt8(const float* p) {
    short8 r;
#pragma unroll
    for (int j = 0; j < 8; ++j) r[j] = (short)f2bf(p[j]);
    return r;
}

__device__ __forceinline__ short8 pack8(floatx4 a, floatx4 b) {
    short8 r;
    r[0] = (short)f2bf(a.x); r[1] = (short)f2bf(a.y);
    r[2] = (short)f2bf(a.z); r[3] = (short)f2bf(a.w);
    r[4] = (short)f2bf(b.x); r[5] = (short)f2bf(b.y);
    r[6] = (short)f2bf(b.z); r[7] = (short)f2bf(b.w);
    return r;
}

// fast sigmoid / tanh: v_exp_f32 (2^x) + v_rcp_f32, ~1 ulp each
#define LOG2E 1.44269504088896f
__device__ __forceinline__ float sigm(float x) {
    return __builtin_amdgcn_rcpf(1.0f + __builtin_amdgcn_exp2f(x * -LOG2E));
}
__device__ __forceinline__ float tanh_(float x) {
    return 2.0f * __builtin_amdgcn_rcpf(1.0f + __builtin_amdgcn_exp2f(x * -2.0f * LOG2E)) - 1.0f;
}

// R5 post-mortem: removing the per-step vmem drain saved only 82cy/step ->
// the step was never drain-bound; it is LATENCY-bound at 1 wave/SIMD
// (Occupancy 11.5%, all pipes <35%). Fix: 2 chains/block x 512 blocks ->
// 2 blocks/CU with INDEPENDENT barriers -> 2 waves/SIMD; block B issues
// while block A waits on barrier / ds_read / MFMA-dep / trans chains.
// Cost: A-row replication 4x->8x (M=2), doubling per-CU MFMA+VALU issue --
// affordable at 34%/27% utilization.
//
// Wave w owns gate classes i,f,g,o for units 16w..16w+15 (unchanged).
// A-frag rows replicated 8x (row = nloc>>3); C row = quad*4+reg ->
// batch row = quad>>1 for all 4 regs; every lane holds its gates
// replicated -> full-wave epilogue, zero cross-lane traffic.
// Chunked global I/O (unchanged from R5): steps 1..7 of each 8-step chunk
// issue zero global ops; chunk loads/stores at sl0, LDS-write at sl1.
// Accumulation order (bias, x kf0..3, h kf0..1) identical -> same absmax.
__global__ __launch_bounds__(256, 2) void lstm_bidir(
    const float* __restrict__ x,
    const float* __restrict__ WihF, const float* __restrict__ WhhF, const float* __restrict__ bF,
    const float* __restrict__ WihB, const float* __restrict__ WhhB, const float* __restrict__ bB,
    float* __restrict__ out)
{
    const int tid  = threadIdx.x;
    const int w    = tid >> 6;       // wave id 0..3
    const int lane = tid & 63;
    const int nloc = lane & 15;      // C col / B n index
    const int quad = lane >> 4;      // A/B k = quad*8 + j
    const int brow = quad >> 1;      // epilogue batch row (0..1)
    const int bid  = blockIdx.x;     // 0..511
    const int dir  = bid & 1;
    const int b0   = (bid >> 1) * ROWS;

    const float* Wih  = dir ? WihB : WihF;
    const float* Whh  = dir ? WhhB : WhhF;
    const float* bias = dir ? bB   : bF;

    // LDS ~19.8KB/block -> 2 blocks/CU = ~40KB of 160KB.
    __shared__ __align__(16) unsigned short xch[2][CH][ROWS * XSTR];
    __shared__ __align__(16) unsigned short h_s[2][ROWS * HSTR];
    __shared__ __align__(16) float obuf[2][CH][ROWS][OSTR];

    for (int i = tid; i < 2 * ROWS * HSTR; i += 256) ((unsigned short*)h_s)[i] = 0;

    // ---- Preload weight B-fragments into registers (one-time) ----
    short8 wihf[4][4];  // [gate class][k-frag of 32]
    short8 whhf[4][2];
    float  bv[4];
#pragma unroll
    for (int gc = 0; gc < 4; ++gc) {
        const int row = gc * 64 + w * 16 + nloc;   // gate index in [0,256)
        bv[gc] = bias[row];
#pragma unroll
        for (int kf = 0; kf < 4; ++kf)
            wihf[gc][kf] = cvt8(Wih + row * IN_DIM + kf * 32 + quad * 8);
#pragma unroll
        for (int kf = 0; kf < 2; ++kf)
            whhf[gc][kf] = cvt8(Whh + row * HID + kf * 32 + quad * 8);
    }

    auto tmap = [&](int s) {
        int ss = s < T_LEN - 1 ? s : T_LEN - 1;
        return dir ? (T_LEN - 1 - ss) : ss;
    };

    // ---- chunk staging mapping: thread (g = tid>>5, l32 = tid&31):
    // row = l32>>4, cols (l32&15)*8 .. +8 ; 16 thr x 32B = 512B contiguous ----
    const int g    = tid >> 5;           // chunk-local step 0..7
    const int l32  = tid & 31;
    const int srow = l32 >> 4;           // 0..1
    const int sc8  = (l32 & 15) * 8;     // col base
    const float* xrow = x + (size_t)(b0 + srow) * T_LEN * IN_DIM + sc8;

    // Prologue: stage chunk 0 directly (load + cvt + ds_write)
    {
        const float* p = xrow + (size_t)tmap(g) * IN_DIM;
        floatx4 v0 = *(const floatx4*)(p);
        floatx4 v1 = *(const floatx4*)(p + 4);
        *(short8*)&xch[0][g][srow * XSTR + sc8] = pack8(v0, v1);
    }

    float c = 0.f;             // cell state for (row=brow, unit=16w+nloc)

    __syncthreads();           // h_s zeroed + chunk 0 staged

    // ---- Prologue: xacc for t=0 from xch[0][0] ----
    floatx4 xacc0[4], xacc1[4];
    {
        short8 xa[4];
        const unsigned short* xb = &xch[0][0][(nloc >> 3) * XSTR + quad * 8];
#pragma unroll
        for (int kf = 0; kf < 4; ++kf) xa[kf] = *(const short8*)(xb + kf * 32);
#pragma unroll
        for (int gc = 0; gc < 4; ++gc) xacc0[gc] = (floatx4){bv[gc], bv[gc], bv[gc], bv[gc]};
#pragma unroll
        for (int kf = 0; kf < 4; ++kf)
#pragma unroll
            for (int gc = 0; gc < 4; ++gc)
                xacc0[gc] = __builtin_amdgcn_mfma_f32_16x16x32_bf16(xa[kf], wihf[gc][kf], xacc0[gc], 0, 0, 0);
    }

    floatx4 stg[2];            // in-flight next-chunk x (issued sl0, written sl1)

    // flush chunk chkPrev: 8 steps x 2 rows x 64 f32 = 1024 f32; 1 float4/thr.
    auto flushPrev = [&](int chkPrev) {
        const int pb = chkPrev & 1;
        const int fs = tid >> 5;          // step
        const int fr = (tid >> 4) & 1;    // row
        const int fu = (tid & 15) * 4;    // unit base
        floatx4 v = *(const floatx4*)&obuf[pb][fs][fr][fu];
        const int tg = tmap(chkPrev * CH + fs);
        *(floatx4*)(out + ((size_t)(b0 + fr) * T_LEN + tg) * 128 + dir * HID + fu) = v;
    };

    auto step = [&](int sl, int chk, int cbuf, floatx4* xaccC, floatx4* xaccN) {
        const int cur = sl & 1;

        if (sl == 0) {
            if (chk > 0) flushPrev(chk - 1);             // stores of prev chunk
            if (chk + 1 < NCH) {                         // issue next-chunk loads
                const float* p = xrow + (size_t)tmap((chk + 1) * CH + g) * IN_DIM;
                stg[0] = *(const floatx4*)(p);
                stg[1] = *(const floatx4*)(p + 4);
            }
        }
        if (sl == 1 && chk + 1 < NCH)        // loads drained by sl0 barrier
            *(short8*)&xch[cbuf ^ 1][g][srow * XSTR + sc8] = pack8(stg[0], stg[1]);

        // critical ds_reads first: h(t) A-frags (8x replicated rows)
        short8 ha[2];
        const unsigned short* hb = &h_s[cur][(nloc >> 3) * HSTR + quad * 8];
#pragma unroll
        for (int kf = 0; kf < 2; ++kf) ha[kf] = *(const short8*)(hb + kf * 32);

        // x(t+1) A-frags: same chunk sl+1, or next chunk's slot 0 at sl==7
        short8 xa[4];
        const unsigned short* xb = (sl + 1 < CH)
            ? &xch[cbuf][sl + 1][(nloc >> 3) * XSTR + quad * 8]
            : &xch[cbuf ^ 1][0][(nloc >> 3) * XSTR + quad * 8];
#pragma unroll
        for (int kf = 0; kf < 4; ++kf) xa[kf] = *(const short8*)(xb + kf * 32);

        // critical chain: 2 h-MFMAs on top of precomputed xaccC
        floatx4 acc[4];
#pragma unroll
        for (int gc = 0; gc < 4; ++gc)
            acc[gc] = __builtin_amdgcn_mfma_f32_16x16x32_bf16(ha[0], whhf[gc][0], xaccC[gc], 0, 0, 0);
#pragma unroll
        for (int gc = 0; gc < 4; ++gc)
            acc[gc] = __builtin_amdgcn_mfma_f32_16x16x32_bf16(ha[1], whhf[gc][1], acc[gc], 0, 0, 0);

        // off-critical: input-gate accumulators for step t+1
#pragma unroll
        for (int gc = 0; gc < 4; ++gc) xaccN[gc] = (floatx4){bv[gc], bv[gc], bv[gc], bv[gc]};
#pragma unroll
        for (int kf = 0; kf < 4; ++kf)
#pragma unroll
            for (int gc = 0; gc < 4; ++gc)
                xaccN[gc] = __builtin_amdgcn_mfma_f32_16x16x32_bf16(xa[kf], wihf[gc][kf], xaccN[gc], 0, 0, 0);

        // epilogue: gates replicated across regs (and across quad pairs) -> [0]
        {
            float iv = sigm(acc[0][0]);
            float fv = sigm(acc[1][0]);
            float gv = tanh_(acc[2][0]);
            float ov = sigm(acc[3][0]);
            c = fv * c + iv * gv;
            float hv = ov * tanh_(c);
            if ((quad & 1) == 0) {           // one writer per (row, unit)
                obuf[cbuf][sl][brow][w * 16 + nloc] = hv;
                h_s[cur ^ 1][brow * HSTR + w * 16 + nloc] = f2bf(hv);
            }
        }
        __syncthreads();
    };

    for (int chk = 0; chk < NCH; ++chk) {
        const int cbuf = chk & 1;
#pragma unroll
        for (int sp = 0; sp < CH; sp += 2) {
            step(sp,     chk, cbuf, xacc0, xacc1);
            step(sp + 1, chk, cbuf, xacc1, xacc0);
        }
    }
    flushPrev(NCH - 1);        // last chunk (after the loop's final barrier)
}

extern "C" void kernel_launch(void* const* d_in, const int* in_sizes, int n_in,
                              void* d_out, int out_size, void* d_ws, size_t ws_size,
                              hipStream_t stream) {
    const float* x    = (const float*)d_in[0];
    const float* WihF = (const float*)d_in[1];
    const float* WhhF = (const float*)d_in[2];
    const float* bF   = (const float*)d_in[3];
    const float* WihB = (const float*)d_in[4];
    const float* WhhB = (const float*)d_in[5];
    const float* bB   = (const float*)d_in[6];
    float* out = (float*)d_out;

    lstm_bidir<<<dim3(512), dim3(256), 0, stream>>>(x, WihF, WhhF, bF, WihB, WhhB, bB, out);
}

// Round 7
// 872.752 us; speedup vs baseline: 1.0163x; 1.0163x over previous
//
#include <hip/hip_runtime.h>

#define T_LEN 1024
#define IN_DIM 128
#define HID 64
#define CH 8              // steps per x-stage / out-flush chunk (= 2 packs)
#define NCH (T_LEN / CH)  // 128 chunks
// LDS row strides. XSTR/HSTR (shorts): 320B/192B == 16 dwords (mod 32) ->
// 2-way bank aliasing on b128 A-frag reads = free (validated R4/R5: ~0/4M).
#define XSTR 160
#define HSTR 96
#define OSTR 72

typedef __attribute__((ext_vector_type(8))) short short8;
typedef __attribute__((ext_vector_type(4))) float floatx4;
typedef __attribute__((ext_vector_type(2))) unsigned uintx2;

__device__ __forceinline__ unsigned short f2bf(float v) {
    union { float f; unsigned u; } a; a.f = v;
    unsigned r = a.u + 0x7FFFu + ((a.u >> 16) & 1u);  // RNE, no NaN inputs here
    return (unsigned short)(r >> 16);
}

__device__ __forceinline__ short8 cvt8(const float* p) {
    short8 r;
#pragma unroll
    for (int j = 0; j < 8; ++j) r[j] = (short)f2bf(p[j]);
    return r;
}

__device__ __forceinline__ float i2f(int v) { union { int i; float f; } u; u.i = v; return u.f; }
__device__ __forceinline__ int   f2i(float v) { union { float f; int i; } u; u.f = v; return u.i; }

// fast sigmoid / tanh: v_exp_f32 (2^x) + v_rcp_f32, ~1 ulp each
#define LOG2E 1.44269504088896f
__device__ __forceinline__ float sigm(float x) {
    return __builtin_amdgcn_rcpf(1.0f + __builtin_amdgcn_exp2f(x * -LOG2E));
}
__device__ __forceinline__ float tanh_(float x) {
    return 2.0f * __builtin_amdgcn_rcpf(1.0f + __builtin_amdgcn_exp2f(x * -2.0f * LOG2E)) - 1.0f;
}

// R6 post-mortem: a 16x16x32 bf16 MFMA occupies ~16cy/SIMD (2495TF peak =>
// 4061 FLOP/cy/CU). R5's 24 MFMAs/wave/step = 384cy feed (31% of the step,
// matches MfmaUtil 34%); R6's 2-wave replication doubled it to 768cy (54%)
// and REGRESSED. Fix: cut MFMA count. The x@Wih part is not recurrent ->
// time-batch it: A-tile = 4 timesteps x 4 batch rows (16 real rows), one set
// of 16 x-MFMAs serves 4 steps (issued 1 kf/step). Per-step redistribution of
// the pack result (lane holds (t=quad,b=reg)) to the h-MFMA C-layout
// (b=quad, replicated) = 4 ds_bpermute + 3 selects per gate class --
// wave-private, no barrier, overlaps the h ds_read. Per-wave per-step MFMAs:
// 24 -> 12 (8 h + 4 x amortized); feed 384 -> 192cy.
// Dot-product inputs & accumulation order (bias, x kf0..3, h kf0..1)
// unchanged -> bit-identical output vs R4/R5 (absmax 0.006378174).
//
// Config: back to R5's 4 chains/block x 256 blocks (1 block/CU, 1 wave/SIMD).
// Chunked global I/O (R5): steps 1..7 of each chunk issue zero global ops.
__global__ __launch_bounds__(256, 1) void lstm_bidir(
    const float* __restrict__ x,
    const float* __restrict__ WihF, const float* __restrict__ WhhF, const float* __restrict__ bF,
    const float* __restrict__ WihB, const float* __restrict__ WhhB, const float* __restrict__ bB,
    float* __restrict__ out)
{
    const int tid  = threadIdx.x;
    const int w    = tid >> 6;       // wave id 0..3
    const int lane = tid & 63;
    const int nloc = lane & 15;      // C col / B n index
    const int quad = lane >> 4;      // A/B k = quad*8 + j ; epilogue batch row
    const int bid  = blockIdx.x;
    const int dir  = bid & 1;
    const int b0   = (bid >> 1) * 4;

    const float* Wih  = dir ? WihB : WihF;
    const float* Whh  = dir ? WhhB : WhhF;
    const float* bias = dir ? bB   : bF;

    __shared__ __align__(16) unsigned short xch[2][CH][4 * XSTR];
    __shared__ __align__(16) unsigned short h_s[2][4 * HSTR];
    __shared__ __align__(16) float obuf[2][CH][4][OSTR];

    for (int i = tid; i < 2 * 4 * HSTR; i += 256) ((unsigned short*)h_s)[i] = 0;

    // ---- Preload weight B-fragments into registers (one-time) ----
    short8 wihf[4][4];  // [gate class][k-frag of 32]
    short8 whhf[4][2];
    float  bv[4];
#pragma unroll
    for (int gc = 0; gc < 4; ++gc) {
        const int row = gc * 64 + w * 16 + nloc;   // gate index in [0,256)
        bv[gc] = bias[row];
#pragma unroll
        for (int kf = 0; kf < 4; ++kf)
            wihf[gc][kf] = cvt8(Wih + row * IN_DIM + kf * 32 + quad * 8);
#pragma unroll
        for (int kf = 0; kf < 2; ++kf)
            whhf[gc][kf] = cvt8(Whh + row * HID + kf * 32 + quad * 8);
    }

    auto tmap = [&](int s) {
        int ss = s < T_LEN - 1 ? s : T_LEN - 1;
        return dir ? (T_LEN - 1 - ss) : ss;
    };

    // ---- chunk staging mapping: thread (g = tid>>5, l32 = tid&31) loads
    // float4 of row i, local step g ----
    const int g   = tid >> 5;
    const int l32 = tid & 31;

    // Prologue: stage chunk 0 directly (load + cvt + ds_write)
#pragma unroll
    for (int i = 0; i < 4; ++i) {
        floatx4 v = *(const floatx4*)(x + (size_t)(b0 + i) * T_LEN * IN_DIM
                                        + (size_t)tmap(g) * IN_DIM + l32 * 4);
        unsigned lo = (unsigned)f2bf(v.x) | ((unsigned)f2bf(v.y) << 16);
        unsigned hi = (unsigned)f2bf(v.z) | ((unsigned)f2bf(v.w) << 16);
        uintx2 p = {lo, hi};
        *(uintx2*)&xch[0][g][i * XSTR + l32 * 4] = p;
    }

    float c = 0.f;             // cell state for (row=quad, unit=16w+nloc)
    const bool q1 = (quad & 1) != 0;
    const bool q2 = (quad & 2) != 0;

    __syncthreads();           // h_s zeroed + chunk 0 staged

    // ---- Prologue: time-batched xacc for pack 0 (steps 0..3) from slots 0..3.
    // A row m = x(t = m>>2, b = m&3); lane reads row (nloc>>2 -> t), b = nloc&3.
    floatx4 TBA[4], TBB[4];
#pragma unroll
    for (int gc = 0; gc < 4; ++gc) TBA[gc] = (floatx4){bv[gc], bv[gc], bv[gc], bv[gc]};
#pragma unroll
    for (int kf = 0; kf < 4; ++kf) {
        short8 xa = *(const short8*)&xch[0][nloc >> 2][(nloc & 3) * XSTR + kf * 32 + quad * 8];
#pragma unroll
        for (int gc = 0; gc < 4; ++gc)
            TBA[gc] = __builtin_amdgcn_mfma_f32_16x16x32_bf16(xa, wihf[gc][kf], TBA[gc], 0, 0, 0);
    }

    floatx4 stg[4];            // in-flight next-chunk x (issued sl0, written sl1)

    // flush chunk chkPrev's outputs from obuf to global (32B/thread).
    auto flushPrev = [&](int chkPrev) {
        const int pb  = chkPrev & 1;
        const int fs  = tid >> 5;
        const int fr  = (tid & 31) >> 3;
        const int fu  = (tid & 7) * 8;
        const float* src = &obuf[pb][fs][fr][fu];
        floatx4 v0 = *(const floatx4*)(src);
        floatx4 v1 = *(const floatx4*)(src + 4);
        const int tg = tmap(chkPrev * CH + fs);
        float* dst = out + ((size_t)(b0 + fr) * T_LEN + tg) * 128 + dir * HID + fu;
        *(floatx4*)(dst)     = v0;
        *(floatx4*)(dst + 4) = v1;
    };

    // One step. sl = chunk slot (compile-time via unroll), tloc = sl&3 = slot
    // within pack. TBuse = current pack's xacc (t=quad, b=reg per lane);
    // TBbuild = next pack's, built kf=tloc per step.
    auto stepT = [&](int sl, int chk, int cbuf, floatx4* TBuse, floatx4* TBbuild) {
        const int cur  = sl & 1;
        const int tloc = sl & 3;

        if (sl == 0) {
            if (chk > 0) flushPrev(chk - 1);             // stores of prev chunk
            if (chk + 1 < NCH) {                         // issue next-chunk loads
                const int tn = (chk + 1) * CH + g;
#pragma unroll
                for (int i = 0; i < 4; ++i)
                    stg[i] = *(const floatx4*)(x + (size_t)(b0 + i) * T_LEN * IN_DIM
                                                 + (size_t)tmap(tn) * IN_DIM + l32 * 4);
            }
        }
        if (sl == 1 && chk + 1 < NCH) {      // loads drained by sl0 barrier
#pragma unroll
            for (int i = 0; i < 4; ++i) {
                unsigned lo = (unsigned)f2bf(stg[i].x) | ((unsigned)f2bf(stg[i].y) << 16);
                unsigned hi = (unsigned)f2bf(stg[i].z) | ((unsigned)f2bf(stg[i].w) << 16);
                uintx2 p = {lo, hi};
                *(uintx2*)&xch[cbuf ^ 1][g][i * XSTR + l32 * 4] = p;
            }
        }

        // redistribute this step's xacc: dest (quad,nloc) needs (t=tloc, b=quad)
        // = reg[quad] of lane (tloc*16 + nloc). 4 bperm (static reg) + select.
        float xg[4];
        {
            const int addr = (tloc * 16 + nloc) * 4;
#pragma unroll
            for (int gc = 0; gc < 4; ++gc) {
                float f0 = i2f(__builtin_amdgcn_ds_bpermute(addr, f2i(TBuse[gc][0])));
                float f1 = i2f(__builtin_amdgcn_ds_bpermute(addr, f2i(TBuse[gc][1])));
                float f2 = i2f(__builtin_amdgcn_ds_bpermute(addr, f2i(TBuse[gc][2])));
                float f3 = i2f(__builtin_amdgcn_ds_bpermute(addr, f2i(TBuse[gc][3])));
                float a  = q1 ? f1 : f0;
                float b_ = q1 ? f3 : f2;
                xg[gc] = q2 ? b_ : a;
            }
        }

        // critical: h(t) A-frags (rows replicated: row = nloc>>2) + 2 h-MFMAs
        short8 ha[2];
        const unsigned short* hb = &h_s[cur][(nloc >> 2) * HSTR + quad * 8];
#pragma unroll
        for (int kf = 0; kf < 2; ++kf) ha[kf] = *(const short8*)(hb + kf * 32);

        floatx4 acc[4];
#pragma unroll
        for (int gc = 0; gc < 4; ++gc) acc[gc] = (floatx4){xg[gc], xg[gc], xg[gc], xg[gc]};
#pragma unroll
        for (int gc = 0; gc < 4; ++gc)
            acc[gc] = __builtin_amdgcn_mfma_f32_16x16x32_bf16(ha[0], whhf[gc][0], acc[gc], 0, 0, 0);
#pragma unroll
        for (int gc = 0; gc < 4; ++gc)
            acc[gc] = __builtin_amdgcn_mfma_f32_16x16x32_bf16(ha[1], whhf[gc][1], acc[gc], 0, 0, 0);

        // build next pack's xacc, kf = tloc (1 ds_read + 4 MFMAs, off-critical).
        // sl<4: next pack = slots 4..7 of this chunk; sl>=4: slots 0..3 of the
        // next chunk's buffer (staged at sl==1; junk in the final chunk --
        // harmless, never consumed).
        {
            const unsigned short* xb = (sl < 4)
                ? &xch[cbuf][4 + (nloc >> 2)][(nloc & 3) * XSTR + tloc * 32 + quad * 8]
                : &xch[cbuf ^ 1][nloc >> 2][(nloc & 3) * XSTR + tloc * 32 + quad * 8];
            short8 xa = *(const short8*)xb;
            if (tloc == 0) {
#pragma unroll
                for (int gc = 0; gc < 4; ++gc)
                    TBbuild[gc] = (floatx4){bv[gc], bv[gc], bv[gc], bv[gc]};
            }
#pragma unroll
            for (int gc = 0; gc < 4; ++gc)
                TBbuild[gc] = __builtin_amdgcn_mfma_f32_16x16x32_bf16(xa, wihf[gc][tloc], TBbuild[gc], 0, 0, 0);
        }

        // epilogue: gates replicated across acc regs -> use [0]
        {
            float iv = sigm(acc[0][0]);
            float fv = sigm(acc[1][0]);
            float gv = tanh_(acc[2][0]);
            float ov = sigm(acc[3][0]);
            c = fv * c + iv * gv;
            float hv = ov * tanh_(c);
            obuf[cbuf][sl][quad][w * 16 + nloc] = hv;            // LDS, not global
            h_s[cur ^ 1][quad * HSTR + w * 16 + nloc] = f2bf(hv);
        }
        __syncthreads();
    };

    for (int chk = 0; chk < NCH; ++chk) {
        const int cbuf = chk & 1;
#pragma unroll
        for (int sl = 0; sl < CH; ++sl) {
            if (sl < 4) stepT(sl, chk, cbuf, TBA, TBB);   // even pack uses TBA
            else        stepT(sl, chk, cbuf, TBB, TBA);   // odd pack uses TBB
        }
    }
    flushPrev(NCH - 1);        // last chunk (after the loop's final barrier)
}

extern "C" void kernel_launch(void* const* d_in, const int* in_sizes, int n_in,
                              void* d_out, int out_size, void* d_ws, size_t ws_size,
                              hipStream_t stream) {
    const float* x    = (const float*)d_in[0];
    const float* WihF = (const float*)d_in[1];
    const float* WhhF = (const float*)d_in[2];
    const float* bF   = (const float*)d_in[3];
    const float* WihB = (const float*)d_in[4];
    const float* WhhB = (const float*)d_in[5];
    const float* bB   = (const float*)d_in[6];
    float* out = (float*)d_out;

    lstm_bidir<<<dim3(256), dim3(256), 0, stream>>>(x, WihF, WhhF, bF, WihB, WhhB, bB, out);
}

// Round 8
// 753.224 us; speedup vs baseline: 1.1776x; 1.1587x over previous
//
#include <hip/hip_runtime.h>

#define T_LEN 1024
#define IN_DIM 128
#define HID 64
#define CH 8              // steps per chunk (= 2 packs of 4)
#define NCH (T_LEN / CH)  // 128 chunks
#define HSTR 96           // h_s row stride (shorts): 192B == 16 dw (mod 32) -> 2-way, free (R4/R5)
#define OSTR 72           // obuf row stride (floats)
// x pack-fragment region: [buf][pack][row n(16)][slot(16 of 8 shorts)],
// slot stored at (s ^ (n&7)). Row stride 256B == 0 (mod 128B), so the XOR
// spreads the 16 rows' same-slot reads over 8 distinct 16B windows -> 2-way.
#define PKROW 128             // shorts per row
#define PKSZ  (16 * PKROW)    // shorts per pack

typedef __attribute__((ext_vector_type(8))) short short8;
typedef __attribute__((ext_vector_type(4))) float floatx4;

__device__ __forceinline__ unsigned short f2bf(float v) {
    union { float f; unsigned u; } a; a.f = v;
    unsigned r = a.u + 0x7FFFu + ((a.u >> 16) & 1u);  // RNE, no NaN inputs here
    return (unsigned short)(r >> 16);
}

__device__ __forceinline__ short8 cvt8(const float* p) {
    short8 r;
#pragma unroll
    for (int j = 0; j < 8; ++j) r[j] = (short)f2bf(p[j]);
    return r;
}

// fast sigmoid / tanh: v_exp_f32 (2^x) + v_rcp_f32, ~1 ulp each
#define LOG2E 1.44269504088896f
__device__ __forceinline__ float sigm(float x) {
    return __builtin_amdgcn_rcpf(1.0f + __builtin_amdgcn_exp2f(x * -LOG2E));
}
__device__ __forceinline__ float tanh_(float x) {
    return 2.0f * __builtin_amdgcn_rcpf(1.0f + __builtin_amdgcn_exp2f(x * -2.0f * LOG2E)) - 1.0f;
}

// R7 post-mortem: in-order issue => step = MFMA pipe spacing (19.4cy each,
// m06 16x16 ceiling) + un-hidden latency. R7 halved MFMAs but put 16
// ds_bpermute (~120cy DS ops) + selects ON the critical path (they gate the
// h-MFMA C-input) -> regressed. Fix: pack A-row permutation m = b*4 + tloc.
// Then D row m = 4*quad + reg => lane (q,n) reg r = x-gates(b=q, t=pack*4+r):
// the per-step xacc is a REGISTER PICK TB[gc][tloc]. Zero redistribution.
// 12 MFMA/wave/step (8 h + 4 pack-build amortized over 4 steps).
// Accumulation order per output unchanged (bias, x kf0..3, h kf0..1) ->
// bit-identical to R4/R5/R7 (absmax 0.006378174 is the tripwire).
//
// One block = 4 batch rows x one dir; 256 blocks; 4 waves; wave w owns gate
// classes i,f,g,o for units 16w..16w+15. h-part A rows read replicated
// (row = nloc>>2) -> every lane holds its gates in all 4 acc regs ->
// full-wave epilogue, no cross-lane traffic. Chunked global I/O (R5):
// steps 1..7 of each chunk issue zero global ops, so their __syncthreads
// vmcnt(0) drain is vacuous; chunk loads/flushes at sl0 (drained once/chunk).
__global__ __launch_bounds__(256, 1) void lstm_bidir(
    const float* __restrict__ x,
    const float* __restrict__ WihF, const float* __restrict__ WhhF, const float* __restrict__ bF,
    const float* __restrict__ WihB, const float* __restrict__ WhhB, const float* __restrict__ bB,
    float* __restrict__ out)
{
    const int tid  = threadIdx.x;
    const int w    = tid >> 6;       // wave id 0..3
    const int lane = tid & 63;
    const int nloc = lane & 15;      // C col / B n index / A row (pack reads)
    const int quad = lane >> 4;      // A/B k = quad*8 + j ; epilogue batch row
    const int bid  = blockIdx.x;
    const int dir  = bid & 1;
    const int b0   = (bid >> 1) * 4;

    const float* Wih  = dir ? WihB : WihF;
    const float* Whh  = dir ? WhhB : WhhF;
    const float* bias = dir ? bB   : bF;

    // LDS: xpk 16KB + h_s 1.5KB + obuf 18KB = ~36KB
    __shared__ __align__(16) unsigned short xpk[2][2][PKSZ];
    __shared__ __align__(16) unsigned short h_s[2][4 * HSTR];
    __shared__ __align__(16) float obuf[2][CH][4][OSTR];

    for (int i = tid; i < 2 * 4 * HSTR; i += 256) ((unsigned short*)h_s)[i] = 0;

    // ---- Preload weight B-fragments into registers (one-time) ----
    short8 wihf[4][4];  // [gate class][k-frag of 32]
    short8 whhf[4][2];
    float  bv[4];
#pragma unroll
    for (int gc = 0; gc < 4; ++gc) {
        const int row = gc * 64 + w * 16 + nloc;   // gate index in [0,256)
        bv[gc] = bias[row];
#pragma unroll
        for (int kf = 0; kf < 4; ++kf)
            wihf[gc][kf] = cvt8(Wih + row * IN_DIM + kf * 32 + quad * 8);
#pragma unroll
        for (int kf = 0; kf < 2; ++kf)
            whhf[gc][kf] = cvt8(Whh + row * HID + kf * 32 + quad * 8);
    }

    auto tmap = [&](int s) {
        int ss = s < T_LEN - 1 ? s : T_LEN - 1;
        return dir ? (T_LEN - 1 - ss) : ss;
    };

    // ---- staging map: thread (g = tid>>5 -> chunk-local t, l32 = tid&31):
    // batch row sb = l32>>3, slot-pair sp = l32&7 (k = 16*sp..16*sp+15).
    // Pack row n = sb*4 + (g&3)  [the m = b*4 + tloc permutation], pack = g>>2.
    const int g   = tid >> 5;
    const int l32 = tid & 31;
    const int sb  = l32 >> 3;
    const int sp  = l32 & 7;
    const int srow = sb * 4 + (g & 3);
    const int spk  = g >> 2;
    const int wo0 = srow * PKROW + (((2 * sp)     ^ (srow & 7)) * 8);
    const int wo1 = srow * PKROW + (((2 * sp + 1) ^ (srow & 7)) * 8);
    const float* xsrc = x + (size_t)(b0 + sb) * T_LEN * IN_DIM + sp * 16;

    // pack A-frag read offsets (lane q,n; kf): row n, slot kf*4+q, swizzled
    int ro[4];
#pragma unroll
    for (int kf = 0; kf < 4; ++kf)
        ro[kf] = nloc * PKROW + ((((kf * 4 + quad) ^ (nloc & 7))) * 8);

    // Prologue: stage both packs of chunk 0
    {
        const float* p = xsrc + (size_t)tmap(g) * IN_DIM;
        *(short8*)&xpk[0][spk][wo0] = cvt8(p);
        *(short8*)&xpk[0][spk][wo1] = cvt8(p + 8);
    }

    float c = 0.f;             // cell state for (row=quad, unit=16w+nloc)

    __syncthreads();           // h_s zeroed + chunk 0 staged

    // ---- Prologue: build TBA = bias + x-gates for pack 0 (steps 0..3) ----
    floatx4 TBA[4], TBB[4];
#pragma unroll
    for (int gc = 0; gc < 4; ++gc) TBA[gc] = (floatx4){bv[gc], bv[gc], bv[gc], bv[gc]};
#pragma unroll
    for (int kf = 0; kf < 4; ++kf) {
        short8 xa = *(const short8*)(&xpk[0][0][0] + ro[kf]);
#pragma unroll
        for (int gc = 0; gc < 4; ++gc)
            TBA[gc] = __builtin_amdgcn_mfma_f32_16x16x32_bf16(xa, wihf[gc][kf], TBA[gc], 0, 0, 0);
    }

    floatx4 stg[4];            // in-flight next-chunk x (issued sl0, written sl1)

    // flush chunk chkPrev's outputs from obuf to global (32B/thread)
    auto flushPrev = [&](int chkPrev) {
        const int pb  = chkPrev & 1;
        const int fs  = tid >> 5;
        const int fr  = (tid & 31) >> 3;
        const int fu  = (tid & 7) * 8;
        const float* src = &obuf[pb][fs][fr][fu];
        floatx4 v0 = *(const floatx4*)(src);
        floatx4 v1 = *(const floatx4*)(src + 4);
        const int tg = tmap(chkPrev * CH + fs);
        float* dst = out + ((size_t)(b0 + fr) * T_LEN + tg) * 128 + dir * HID + fu;
        *(floatx4*)(dst)     = v0;
        *(floatx4*)(dst + 4) = v1;
    };

    // One step; sl is compile-time (unrolled). Slots 0-3 use TBA & build TBB
    // (pack 1 of cbuf); slots 4-7 use TBB & build TBA (pack 0 of cbuf^1,
    // staged at sl1 of this chunk -- barrier-separated).
    auto stepT = [&](int sl, int chk, int cbuf, floatx4* TBuse, floatx4* TBbuild) {
        const int cur  = sl & 1;
        const int tloc = sl & 3;

        if (sl == 0) {
            if (chk > 0) flushPrev(chk - 1);             // stores of prev chunk
            if (chk + 1 < NCH) {                         // issue next-chunk loads
                const float* p = xsrc + (size_t)tmap((chk + 1) * CH + g) * IN_DIM;
#pragma unroll
                for (int i = 0; i < 4; ++i)
                    stg[i] = *(const floatx4*)(p + i * 4);
            }
        }
        if (sl == 1 && chk + 1 < NCH) {      // loads drained by sl0 barrier
            *(short8*)&xpk[cbuf ^ 1][spk][wo0] = cvt8((const float*)&stg[0]);
            *(short8*)&xpk[cbuf ^ 1][spk][wo1] = cvt8((const float*)&stg[2]);
        }

        // critical ds_reads first: h(t) A-frags (rows replicated: row=nloc>>2)
        short8 ha[2];
        const unsigned short* hb = &h_s[cur][(nloc >> 2) * HSTR + quad * 8];
#pragma unroll
        for (int kf = 0; kf < 2; ++kf) ha[kf] = *(const short8*)(hb + kf * 32);

        // pack-build A-frag (off-critical): kf = tloc
        const bool doBuild = (sl < 4) || (chk + 1 < NCH);
        const unsigned short* pkb = (sl < 4) ? &xpk[cbuf][1][0] : &xpk[cbuf ^ 1][0][0];
        short8 xa = *(const short8*)(pkb + ro[tloc]);

        // critical chain: xacc = register pick; + 2 dep h-MFMAs
        floatx4 acc[4];
#pragma unroll
        for (int gc = 0; gc < 4; ++gc) {
            const float xg = TBuse[gc][tloc];
            acc[gc] = (floatx4){xg, xg, xg, xg};
        }
#pragma unroll
        for (int gc = 0; gc < 4; ++gc)
            acc[gc] = __builtin_amdgcn_mfma_f32_16x16x32_bf16(ha[0], whhf[gc][0], acc[gc], 0, 0, 0);
#pragma unroll
        for (int gc = 0; gc < 4; ++gc)
            acc[gc] = __builtin_amdgcn_mfma_f32_16x16x32_bf16(ha[1], whhf[gc][1], acc[gc], 0, 0, 0);

        // build next pack's TB: 1 kf per step (4 MFMAs), fills latency shadow
        if (doBuild) {
            if (tloc == 0) {
#pragma unroll
                for (int gc = 0; gc < 4; ++gc)
                    TBbuild[gc] = (floatx4){bv[gc], bv[gc], bv[gc], bv[gc]};
            }
#pragma unroll
            for (int gc = 0; gc < 4; ++gc)
                TBbuild[gc] = __builtin_amdgcn_mfma_f32_16x16x32_bf16(xa, wihf[gc][tloc], TBbuild[gc], 0, 0, 0);
        }

        // epilogue: gates replicated across acc regs -> use [0]
        {
            float iv = sigm(acc[0][0]);
            float fv = sigm(acc[1][0]);
            float gv = tanh_(acc[2][0]);
            float ov = sigm(acc[3][0]);
            c = fv * c + iv * gv;
            float hv = ov * tanh_(c);
            obuf[cbuf][sl][quad][w * 16 + nloc] = hv;            // LDS, not global
            h_s[cur ^ 1][quad * HSTR + w * 16 + nloc] = f2bf(hv);
        }
        __syncthreads();
    };

    for (int chk = 0; chk < NCH; ++chk) {
        const int cbuf = chk & 1;
#pragma unroll
        for (int sl = 0; sl < CH; ++sl) {
            if (sl < 4) stepT(sl, chk, cbuf, TBA, TBB);   // even pack
            else        stepT(sl, chk, cbuf, TBB, TBA);   // odd pack
        }
    }
    flushPrev(NCH - 1);        // last chunk (after the loop's final barrier)
}

extern "C" void kernel_launch(void* const* d_in, const int* in_sizes, int n_in,
                              void* d_out, int out_size, void* d_ws, size_t ws_size,
                              hipStream_t stream) {
    const float* x    = (const float*)d_in[0];
    const float* WihF = (const float*)d_in[1];
    const float* WhhF = (const float*)d_in[2];
    const float* bF   = (const float*)d_in[3];
    const float* WihB = (const float*)d_in[4];
    const float* WhhB = (const float*)d_in[5];
    const float* bB   = (const float*)d_in[6];
    float* out = (float*)d_out;

    lstm_bidir<<<dim3(256), dim3(256), 0, stream>>>(x, WihF, WhhF, bF, WihB, WhhB, bB, out);
}